// Round 6
// baseline (242.624 us; speedup 1.0000x reference)
//
#include <hip/hip_runtime.h>
#include <cmath>

#define H 8
#define SEQ 2048
#define EDIM 512
#define HD 64
#define EPSF 1e-15f

typedef short bf16x8 __attribute__((ext_vector_type(8)));
typedef float f32x4 __attribute__((ext_vector_type(4)));

// workspace layout (float offsets; 16B-aligned)
#define ZN_OFF    16                                // 8 bi-slots x 3 x EDIM partial sums
#define STATS_OFF (ZN_OFF + 24 * EDIM)              // 3*H*SEQ fp32 (rounded q2/k2/v2)
#define CQ_OFF    (STATS_OFF + 3 * H * SEQ)         // H*SEQ: 2/(1-q2)
#define IK_OFF    (CQ_OFF + H * SEQ)                // H*SEQ: 1/(1-k2)
#define PX2_OFF   (IK_OFF + H * SEQ)                // (legacy, keeps offsets stable)
#define U16_OFF   (PX2_OFF + 12288 + 16)
#define WT_U16    0
#define QKVB_U16  (WT_U16 + 3 * EDIM * EDIM)
#define VT_U16    (QKVB_U16 + 3 * SEQ * EDIM)
#define U16_TOTAL (VT_U16 + H * 80 * SEQ)
#define BIG_OFF   (U16_OFF + U16_TOTAL / 2 + 16)    // attn partials (43.3MB)
// Chunk-major decomposition. Slot per (q-subtile s, 64-key chunk c), c<=s>>2.
// Slots per head = sum_s (s/4+1) = 2112; base(s) = s + 2a(a-1) + a*b, a=s>>2, b=s&3.
#define TRI16 2112
#define PART_U16S (H * TRI16 * 1280)                // 21,626,880 u16 = 43.3 MB
#define ACC_FLOATS  (H * SEQ * 80)

__device__ __forceinline__ float bf2f(unsigned short u){
  union { unsigned int i; float f; } v; v.i = ((unsigned int)u) << 16; return v.f;
}
__device__ __forceinline__ unsigned short f2bf(float f){
  union { float f; unsigned int i; } v; v.f = f;
  unsigned int x = v.i;
  unsigned int r = (x + 0x7fffu + ((x >> 16) & 1u)) >> 16;
  return (unsigned short)r;
}

// micro-ops: single-instruction packed bf16 convert + raw transcendentals.
__device__ __forceinline__ unsigned int cvt_pk_bf16(float a, float b){
  unsigned int r;
  asm("v_cvt_pk_bf16_f32 %0, %1, %2" : "=v"(r) : "v"(a), "v"(b));
  return r;
}
__device__ __forceinline__ float vlog2f(float x){
  float r; asm("v_log_f32 %0, %1" : "=v"(r) : "v"(x)); return r;
}
__device__ __forceinline__ float vexp2f(float x){
  float r; asm("v_exp_f32 %0, %1" : "=v"(r) : "v"(x)); return r;
}
__device__ __forceinline__ float vsqrtf(float x){
  float r; asm("v_sqrt_f32 %0, %1" : "=v"(r) : "v"(x)); return r;
}

// inline dtype detect (fp32 data bf16-decodes to huge magnitudes w.p. ~1)
__device__ __forceinline__ int detect_f32(const unsigned short* __restrict__ q){
  const int l = threadIdx.x & 63;
  float mx = 0.f;
  #pragma unroll
  for (int j = 0; j < 4; ++j) mx = fmaxf(mx, fabsf(bf2f(q[l * 4 + j])));
  #pragma unroll
  for (int m = 32; m >= 1; m >>= 1) mx = fmaxf(mx, __shfl_xor(mx, m, 64));
  return mx > 1000.f;
}

// slot base for q-subtile s: sum_{u<s} (u/4 + 1)
__device__ __forceinline__ int sbase(int s){
  const int a = s >> 2, b = s & 3;
  return s + 2 * a * (a - 1) + a * b;
}

// P1: W -> WT bf16 [p][o][i] (transpose) + per-bi partial column sumsq (no atomics).
__global__ __launch_bounds__(256) void wcvt_kernel(
    const void* __restrict__ Wq, const void* __restrict__ Wk, const void* __restrict__ Wv,
    const unsigned short* __restrict__ qprobe,
    unsigned short* __restrict__ WT, float* __restrict__ zn)
{
  const int p = blockIdx.y;
  const int bi = blockIdx.x >> 3, bo = blockIdx.x & 7;
  const void* W = (p == 0) ? Wq : ((p == 1) ? Wk : Wv);
  const int t = threadIdx.x;
  const int isf32 = detect_f32(qprobe);
  __shared__ float tile[64][65];

  #pragma unroll
  for (int j = 0; j < 16; ++j){
    int idx = t + 256 * j;
    int il = idx >> 6, ol = idx & 63;
    float val;
    if (isf32) val = ((const float*)W)[(size_t)(bi * 64 + il) * EDIM + bo * 64 + ol];
    else       val = bf2f(((const unsigned short*)W)[(size_t)(bi * 64 + il) * EDIM + bo * 64 + ol]);
    tile[il][ol] = val;
  }
  __syncthreads();
  if (t < 64){
    float s = 0.f;
    #pragma unroll 8
    for (int i = 0; i < 64; ++i){ float v = tile[i][t]; s += v * v; }
    zn[((size_t)(bi * 3 + p)) * EDIM + bo * 64 + t] = s;
  }
  #pragma unroll
  for (int j = 0; j < 16; ++j){
    int idx = t + 256 * j;
    int ol = idx >> 6, il = idx & 63;
    WT[((size_t)p * EDIM + bo * 64 + ol) * EDIM + bi * 64 + il] = f2bf(tile[il][ol]);
  }
}

// K1 (R28): FUSED projection, 512 threads / 8 waves. Wave (cg, ks): 128 cols
// (cg) x K-half (ks*256). Restores the proven R22 per-wave GEMM shape (8
// K-steps, full double-buffer) at 2x waves/CU; K-halves combined in-block via
// LDS; transform and output phases run on all 512 threads at half depth.
// Grid (128, 3), 512 threads.
__global__ __launch_bounds__(512) void hlin_kernel(
    const void* __restrict__ Xq, const void* __restrict__ Xk, const void* __restrict__ Xv,
    const unsigned short* __restrict__ WT,
    const void* __restrict__ Bq, const void* __restrict__ Bk, const void* __restrict__ Bv,
    const float* __restrict__ znacc, const unsigned short* __restrict__ qprobe,
    unsigned short* __restrict__ qkvb, float* __restrict__ stats,
    float* __restrict__ cqs, float* __restrict__ iks,
    unsigned short* __restrict__ VT)
{
  const int p = blockIdx.y;
  const void* X  = (p == 0) ? Xq : ((p == 1) ? Xk : Xv);
  const void* Bb = (p == 0) ? Bq : ((p == 1) ? Bk : Bv);
  const int rg = blockIdx.x;
  const int r0 = rg * 16;
  const int t  = threadIdx.x;
  const int w8 = t >> 6, lane = t & 63;
  const int cg = w8 >> 1, ks = w8 & 1;
  const int col = lane & 15, quad = lane >> 4;
  const int isf32 = detect_f32(qprobe);

  __shared__ float smem[16 * EDIM];
  __shared__ float sw2[16];
  __shared__ float sx2[2][16];

  const int koff = ks * 256;
  const unsigned short* WTb = WT + ((size_t)p * EDIM + cg * 128 + col) * EDIM + koff;
  const float* Xf = (const float*)X + (size_t)(r0 + col) * EDIM + koff;
  const unsigned short* Xh = (const unsigned short*)X + (size_t)(r0 + col) * EDIM + koff;

  f32x4 acc[8];
  #pragma unroll
  for (int nt = 0; nt < 8; ++nt) acc[nt] = (f32x4){0.f, 0.f, 0.f, 0.f};
  float x2part = 0.f;

  bf16x8 caf, naf;
  bf16x8 cbf[8], nbf[8];
  {
    if (isf32){
      float4 xa = *(const float4*)&Xf[quad * 8];
      float4 xb = *(const float4*)&Xf[quad * 8 + 4];
      float xv[8] = {xa.x, xa.y, xa.z, xa.w, xb.x, xb.y, xb.z, xb.w};
      #pragma unroll
      for (int j = 0; j < 8; ++j){ caf[j] = (short)f2bf(xv[j]); x2part += xv[j] * xv[j]; }
    } else {
      caf = *(const bf16x8*)&Xh[quad * 8];
      #pragma unroll
      for (int j = 0; j < 8; ++j){ float xv = bf2f((unsigned short)caf[j]); x2part += xv * xv; }
    }
    #pragma unroll
    for (int nt = 0; nt < 8; ++nt)
      cbf[nt] = *(const bf16x8*)&WTb[(size_t)nt * 16 * EDIM + quad * 8];
  }

  for (int st = 0; st < 8; ++st){
    if (st + 1 < 8){
      const int off = (st + 1) * 32 + quad * 8;
      if (isf32){
        float4 xa = *(const float4*)&Xf[off];
        float4 xb = *(const float4*)&Xf[off + 4];
        float xv[8] = {xa.x, xa.y, xa.z, xa.w, xb.x, xb.y, xb.z, xb.w};
        #pragma unroll
        for (int j = 0; j < 8; ++j){ naf[j] = (short)f2bf(xv[j]); x2part += xv[j] * xv[j]; }
      } else {
        naf = *(const bf16x8*)&Xh[off];
        #pragma unroll
        for (int j = 0; j < 8; ++j){ float xv = bf2f((unsigned short)naf[j]); x2part += xv * xv; }
      }
      #pragma unroll
      for (int nt = 0; nt < 8; ++nt)
        nbf[nt] = *(const bf16x8*)&WTb[(size_t)nt * 16 * EDIM + off];
    }
    #pragma unroll
    for (int nt = 0; nt < 8; ++nt)
      acc[nt] = __builtin_amdgcn_mfma_f32_16x16x32_bf16(caf, cbf[nt], acc[nt], 0, 0, 0);
    if (st + 1 < 8){
      caf = naf;
      #pragma unroll
      for (int nt = 0; nt < 8; ++nt) cbf[nt] = nbf[nt];
    }
  }
  // per-K-half row x2 (full over this wave's K range after quad reduction)
  x2part += __shfl_xor(x2part, 16, 64);
  x2part += __shfl_xor(x2part, 32, 64);
  if (cg == 0 && quad == 0) sx2[ks][col] = x2part;

  // partial exchange: park the 4 acc tiles this wave does NOT own.
  // ks=0 owns nt 0..3 (parks 4..7); ks=1 owns nt 4..7 (parks 0..3).
  {
    const int park = (ks == 0) ? 4 : 0;
    #pragma unroll
    for (int j = 0; j < 4; ++j){
      const int nt = park + j;
      const int n = cg * 128 + nt * 16 + col;
      #pragma unroll
      for (int r = 0; r < 4; ++r)
        smem[(quad * 4 + r) * EDIM + n] = acc[nt][r];
    }
  }
  __syncthreads();
  const int ntb = ks * 4;   // owned tile base
  #pragma unroll
  for (int j = 0; j < 4; ++j){
    const int nt = ntb + j;
    const int n = cg * 128 + nt * 16 + col;
    #pragma unroll
    for (int r = 0; r < 4; ++r)
      acc[nt][r] += smem[(quad * 4 + r) * EDIM + n];
  }

  float lamr[4], lm1[4];
  #pragma unroll
  for (int r = 0; r < 4; ++r){
    float x2r = sx2[0][quad * 4 + r] + sx2[1][quad * 4 + r];
    lamr[r] = 2.f / (1.f - x2r);
    lm1[r] = lamr[r] - 1.f;
  }
  // transform owned tiles (4 per thread), write back into smem
  #pragma unroll
  for (int j = 0; j < 4; ++j){
    const int nt = ntb + j;
    const int n = cg * 128 + nt * 16 + col;
    float zsum = 0.f;
    #pragma unroll
    for (int bi = 0; bi < 8; ++bi)
      zsum += znacc[((size_t)(bi * 3 + p)) * EDIM + n];
    float znv = fmaxf(sqrtf(zsum), EPSF);
    float rb;
    if (isf32) rb = ((const float*)Bb)[n];
    else       rb = bf2f(((const unsigned short*)Bb)[n]);
    float e2r = __expf(2.f * rb);
    float ie2r = 1.f / e2r;
    float ch = 0.5f * (e2r + ie2r), sh = 0.5f * (e2r - ie2r);
    float izn = 1.f / znv;
    float tz = 2.f * znv;
    #pragma unroll
    for (int r = 0; r < 4; ++r){
      float a = (acc[nt][r] * lamr[r] * izn) * ch - lm1[r] * sh;
      float b = a + sqrtf(a * a + 1.f);
      float tt = __expf(tz * __logf(b));
      smem[(quad * 4 + r) * EDIM + n] = 0.5f * (tt - 1.f / tt);
    }
  }
  __syncthreads();

  // row sumsq: 32 threads per row (16 iterations)
  {
    int row = t >> 5, l = t & 31;
    float s = 0.f;
    for (int o = l; o < EDIM; o += 32){ float wv = smem[row * EDIM + o]; s += wv * wv; }
    #pragma unroll
    for (int m = 16; m >= 1; m >>= 1) s += __shfl_xor(s, m, 32);
    if (l == 0) sw2[row] = s;
  }
  __syncthreads();

  // output: thread halves handle 8 rows each
  const int th = t & 255;
  const int half = t >> 8;
  const int o0 = 2 * th;
  const int h0 = th >> 5;
  const int d0 = o0 & 63;
  const int l5 = th & 31;
  #pragma unroll
  for (int jr = 0; jr < 8; ++jr){
    const int rr = half * 8 + jr;
    float inv = 1.f / (1.f + sqrtf(1.f + sw2[rr]));
    unsigned short b0 = f2bf(smem[rr * EDIM + o0] * inv);
    unsigned short b1 = f2bf(smem[rr * EDIM + o0 + 1] * inv);
    float r0v = bf2f(b0), r1v = bf2f(b1);
    int s = r0 + rr;
    unsigned int* dst = (unsigned int*)&qkvb[(((size_t)p * H + h0) * SEQ + s) * HD + d0];
    *dst = (unsigned int)b0 | ((unsigned int)b1 << 16);
    float ss = r0v * r0v + r1v * r1v;
    #pragma unroll
    for (int m = 16; m >= 1; m >>= 1) ss += __shfl_xor(ss, m, 64);
    if (p == 2){
      float lam = 2.f / (1.f - ss);
      VT[((size_t)h0 * 80 + d0) * SEQ + s]     = f2bf(r0v * lam);
      VT[((size_t)h0 * 80 + d0 + 1) * SEQ + s] = f2bf(r1v * lam);
      if (l5 < 16)
        VT[((size_t)h0 * 80 + 64 + l5) * SEQ + s] = (l5 == 0) ? f2bf(lam - 1.f) : 0;
    }
    if (l5 == 0){
      stats[((size_t)p * H + h0) * SEQ + s] = ss;
      if (p == 0) cqs[(size_t)h0 * SEQ + s] = 2.f / (1.f - ss);
      if (p == 1) iks[(size_t)h0 * SEQ + s] = 1.f / (1.f - ss);
    }
  }
}

// ---- attention helpers ----
__device__ __forceinline__ uint4 xpose32(unsigned int tlo0, unsigned int tlo1,
                                         unsigned int thi0, unsigned int thi1,
                                         int srcA, int srcB, int tsel){
  unsigned int a0 = (unsigned int)__shfl((int)tlo0, srcA, 64);
  unsigned int a1 = (unsigned int)__shfl((int)tlo1, srcA, 64);
  unsigned int b0 = (unsigned int)__shfl((int)thi0, srcA, 64);
  unsigned int b1 = (unsigned int)__shfl((int)thi1, srcA, 64);
  unsigned int c0 = (unsigned int)__shfl((int)tlo0, srcB, 64);
  unsigned int c1 = (unsigned int)__shfl((int)tlo1, srcB, 64);
  unsigned int d0 = (unsigned int)__shfl((int)thi0, srcB, 64);
  unsigned int d1 = (unsigned int)__shfl((int)thi1, srcB, 64);
  uint4 r;
  r.x = tsel ? a1 : a0;
  r.y = tsel ? b1 : b0;
  r.z = tsel ? c1 : c0;
  r.w = tsel ? d1 : d0;
  return r;
}

__device__ __forceinline__ void score4(
    const f32x4& s4, const float4& k2v, const float4& ikv,
    float cq, float cqq2, float m2cq, int kbase, int qmax, int quad,
    float m_et, float m_g2, unsigned int& lo, unsigned int& hi)
{
  float w[4];
  #pragma unroll
  for (int r = 0; r < 4; ++r){
    float k2 = (r == 0) ? k2v.x : (r == 1) ? k2v.y : (r == 2) ? k2v.z : k2v.w;
    float ik = (r == 0) ? ikv.x : (r == 1) ? ikv.y : (r == 2) ? ikv.z : ikv.w;
    float t1 = __builtin_fmaf(k2, cq, cqq2);
    t1 = __builtin_fmaf(m2cq, s4[r], t1);
    float u = fmaxf(t1 * ik, 1e-7f);
    float z = 1.f + u + vsqrtf(u * (u + 2.f));
    float wv = vexp2f(__builtin_fmaf(vlog2f(z), m_et, m_g2));
    const int key = kbase + quad * 4 + r;
    w[r] = (key > qmax) ? 0.f : wv;
  }
  lo = cvt_pk_bf16(w[0], w[1]);
  hi = cvt_pk_bf16(w[2], w[3]);
}

// K3a: attention — R25 structure (proven). Chunk-major: each wave owns one
// 64-key chunk c and a slice of 8 q-subtiles; K/VT/k2/ik fragments are
// loop-invariant; inner loop walks q-subtile pairs with 1-deep Q prefetch.
// Grid (512, H), 64 threads.
template<int NITER>
__device__ __forceinline__ void attn_qloop(
    int s0, int c, int kBeg, int col, int quad, int lane,
    const unsigned short* __restrict__ Qh,
    const bf16x8 (&kf0)[4], const bf16x8 (&kf1)[4],
    const float4 (&ck2)[4], const float4 (&cik)[4],
    const bf16x8 (&vf0)[5], const bf16x8 (&vf1)[5],
    const float* __restrict__ q2s, const float* __restrict__ cqs,
    float m_et, float m_g2, int srcA, int srcB, int tsel,
    float* __restrict__ big, int h, int use_part)
{
  bf16x8 qA0 = *(const bf16x8*)&Qh[(size_t)(s0 * 16 + col) * HD + quad * 8];
  bf16x8 qA1 = *(const bf16x8*)&Qh[(size_t)(s0 * 16 + col) * HD + 32 + quad * 8];
  bf16x8 qB0 = *(const bf16x8*)&Qh[(size_t)((s0 + 1) * 16 + col) * HD + quad * 8];
  bf16x8 qB1 = *(const bf16x8*)&Qh[(size_t)((s0 + 1) * 16 + col) * HD + 32 + quad * 8];
  float q2A = q2s[s0 * 16 + col],       cqA = cqs[s0 * 16 + col];
  float q2B = q2s[(s0 + 1) * 16 + col], cqB = cqs[(s0 + 1) * 16 + col];

  #pragma unroll
  for (int i = 0; i < NITER; ++i){
    const int sA = s0 + 2 * i, sB = sA + 1;
    bf16x8 nA0, nA1, nB0, nB1;
    float nq2A, ncqA, nq2B, ncqB;
    if (i + 1 < NITER){
      const int tA = (sA + 2) * 16 + col, tB = (sA + 3) * 16 + col;
      nA0 = *(const bf16x8*)&Qh[(size_t)tA * HD + quad * 8];
      nA1 = *(const bf16x8*)&Qh[(size_t)tA * HD + 32 + quad * 8];
      nB0 = *(const bf16x8*)&Qh[(size_t)tB * HD + quad * 8];
      nB1 = *(const bf16x8*)&Qh[(size_t)tB * HD + 32 + quad * 8];
      nq2A = q2s[tA]; ncqA = cqs[tA];
      nq2B = q2s[tB]; ncqB = cqs[tB];
    }

    const float cqq2A = cqA * q2A, m2cqA = -2.f * cqA;
    const float cqq2B = cqB * q2B, m2cqB = -2.f * cqB;
    const int qmaxA = sA * 16 + col, qmaxB = sB * 16 + col;

    f32x4 sSA[4], sSB[4];
    __builtin_amdgcn_s_setprio(1);
    #pragma unroll
    for (int g = 0; g < 4; ++g){
      f32x4 z4 = (f32x4){0.f, 0.f, 0.f, 0.f};
      sSA[g] = __builtin_amdgcn_mfma_f32_16x16x32_bf16(kf0[g], qA0, z4, 0, 0, 0);
      sSA[g] = __builtin_amdgcn_mfma_f32_16x16x32_bf16(kf1[g], qA1, sSA[g], 0, 0, 0);
      sSB[g] = __builtin_amdgcn_mfma_f32_16x16x32_bf16(kf0[g], qB0, z4, 0, 0, 0);
      sSB[g] = __builtin_amdgcn_mfma_f32_16x16x32_bf16(kf1[g], qB1, sSB[g], 0, 0, 0);
    }
    __builtin_amdgcn_s_setprio(0);

    unsigned int loA[4], hiA[4], loB[4], hiB[4];
    #pragma unroll
    for (int g = 0; g < 4; ++g){
      score4(sSA[g], ck2[g], cik[g], cqA, cqq2A, m2cqA, kBeg + g * 16, qmaxA, quad,
             m_et, m_g2, loA[g], hiA[g]);
      score4(sSB[g], ck2[g], cik[g], cqB, cqq2B, m2cqB, kBeg + g * 16, qmaxB, quad,
             m_et, m_g2, loB[g], hiB[g]);
    }

    union { uint4 u; bf16x8 v; } pA01, pA23, pB01, pB23;
    pA01.u = xpose32(loA[0], loA[1], hiA[0], hiA[1], srcA, srcB, tsel);
    pA23.u = xpose32(loA[2], loA[3], hiA[2], hiA[3], srcA, srcB, tsel);
    pB01.u = xpose32(loB[0], loB[1], hiB[0], hiB[1], srcA, srcB, tsel);
    pB23.u = xpose32(loB[2], loB[3], hiB[2], hiB[3], srcA, srcB, tsel);

    f32x4 pvA[5], pvB[5];
    __builtin_amdgcn_s_setprio(1);
    #pragma unroll
    for (int nt = 0; nt < 5; ++nt){
      f32x4 z4 = (f32x4){0.f, 0.f, 0.f, 0.f};
      pvA[nt] = __builtin_amdgcn_mfma_f32_16x16x32_bf16(pA01.v, vf0[nt], z4, 0, 0, 0);
      pvA[nt] = __builtin_amdgcn_mfma_f32_16x16x32_bf16(pA23.v, vf1[nt], pvA[nt], 0, 0, 0);
      pvB[nt] = __builtin_amdgcn_mfma_f32_16x16x32_bf16(pB01.v, vf0[nt], z4, 0, 0, 0);
      pvB[nt] = __builtin_amdgcn_mfma_f32_16x16x32_bf16(pB23.v, vf1[nt], pvB[nt], 0, 0, 0);
    }
    __builtin_amdgcn_s_setprio(0);

    if (use_part){
      uint2* slotA = (uint2*)big + (size_t)(h * TRI16 + sbase(sA) + c) * 320;
      uint2* slotB = (uint2*)big + (size_t)(h * TRI16 + sbase(sB) + c) * 320;
      #pragma unroll
      for (int nt = 0; nt < 5; ++nt){
        uint2 pk;
        pk.x = cvt_pk_bf16(pvA[nt][0], pvA[nt][1]);
        pk.y = cvt_pk_bf16(pvA[nt][2], pvA[nt][3]);
        slotA[nt * 64 + lane] = pk;
        pk.x = cvt_pk_bf16(pvB[nt][0], pvB[nt][1]);
        pk.y = cvt_pk_bf16(pvB[nt][2], pvB[nt][3]);
        slotB[nt * 64 + lane] = pk;
      }
    } else {
      #pragma unroll
      for (int r = 0; r < 4; ++r){
        float* rowA = big + ((size_t)h * SEQ + sA * 16 + quad * 4 + r) * 80;
        float* rowB = big + ((size_t)h * SEQ + sB * 16 + quad * 4 + r) * 80;
        #pragma unroll
        for (int nt = 0; nt < 5; ++nt){
          atomicAdd(&rowA[16 * nt + col], pvA[nt][r]);
          atomicAdd(&rowB[16 * nt + col], pvB[nt][r]);
        }
      }
    }

    if (i + 1 < NITER){
      qA0 = nA0; qA1 = nA1; qB0 = nB0; qB1 = nB1;
      q2A = nq2A; cqA = ncqA; q2B = nq2B; cqB = ncqB;
    }
  }
}

__global__ __launch_bounds__(64, 2) void attn_kernel(
    const unsigned short* __restrict__ Qb, const unsigned short* __restrict__ Kb,
    const unsigned short* __restrict__ VT,
    const float* __restrict__ q2s_all, const float* __restrict__ k2s_all,
    const float* __restrict__ cqs_all, const float* __restrict__ iks_all,
    const void* __restrict__ tau, const void* __restrict__ gam,
    const unsigned short* __restrict__ qprobe,
    float* __restrict__ big, int use_part)
{
  const int h = blockIdx.y;
  const int c = blockIdx.x >> 4;            // 64-key chunk
  const int j = blockIdx.x & 15;            // q-slice within chunk
  const int nsl = (33 - c) >> 1;            // ceil((32-c)/2)
  if (j >= nsl) return;
  const int kBeg = c * 64;
  const int s0 = 4 * c + 8 * j;             // first q-subtile of slice
  const int rem = 128 - s0;                 // subtiles remaining (>=4, mult of 4)
  const int lane = threadIdx.x;
  const int col = lane & 15, quad = lane >> 4;

  const unsigned short* Qh  = Qb + (size_t)h * SEQ * HD;
  const unsigned short* Kh  = Kb + (size_t)h * SEQ * HD;
  const unsigned short* VTh = VT + (size_t)h * 80 * SEQ;
  const float* q2s = q2s_all + (size_t)h * SEQ;
  const float* k2s = k2s_all + (size_t)h * SEQ;
  const float* cqs = cqs_all + (size_t)h * SEQ;
  const float* iks = iks_all + (size_t)h * SEQ;

  const int isf32 = detect_f32(qprobe);
  float tauv, gamv;
  if (isf32){ tauv = ((const float*)tau)[0]; gamv = ((const float*)gam)[0]; }
  else      { tauv = bf2f(((const unsigned short*)tau)[0]);
              gamv = bf2f(((const unsigned short*)gam)[0]); }
  // w = exp(-e^tau * ln z - gam) = 2^( log2(z)*(-e^tau) + (-gam*log2e) )
  const float m_et = -__expf(tauv);
  const float m_g2 = -gamv * 1.44269504088896340736f;

  const int srcA = ((quad & 1) * 2) * 16 + col;
  const int srcB = srcA + 16;
  const int tsel = quad >> 1;

  // loop-invariant K-side fragments: 8 K + 10 VT + 8 stat loads, once per wave.
  bf16x8 kf0[4], kf1[4];
  float4 ck2[4], cik[4];
  #pragma unroll
  for (int g = 0; g < 4; ++g){
    kf0[g] = *(const bf16x8*)&Kh[(size_t)(kBeg + g * 16 + col) * HD + quad * 8];
    kf1[g] = *(const bf16x8*)&Kh[(size_t)(kBeg + g * 16 + col) * HD + 32 + quad * 8];
    ck2[g] = *(const float4*)&k2s[kBeg + g * 16 + quad * 4];
    cik[g] = *(const float4*)&iks[kBeg + g * 16 + quad * 4];
  }
  bf16x8 vf0[5], vf1[5];
  #pragma unroll
  for (int nt = 0; nt < 5; ++nt){
    vf0[nt] = *(const bf16x8*)&VTh[(size_t)(16 * nt + col) * SEQ + kBeg + quad * 8];
    vf1[nt] = *(const bf16x8*)&VTh[(size_t)(16 * nt + col) * SEQ + kBeg + 32 + quad * 8];
  }

  if (rem >= 8)
    attn_qloop<4>(s0, c, kBeg, col, quad, lane, Qh, kf0, kf1, ck2, cik, vf0, vf1,
                  q2s, cqs, m_et, m_g2, srcA, srcB, tsel, big, h, use_part);
  else
    attn_qloop<2>(s0, c, kBeg, col, quad, lane, Qh, kf0, kf1, ck2, cik, vf0, vf1,
                  q2s, cqs, m_et, m_g2, srcA, srcB, tsel, big, h, use_part);
}

// K3b: bf16-slice-sum + LDS reduce + gyromidpoint. Grid (128, H), 256 thr.
// blockIdx.x = q-subtile s; reduce over chunks c = 0..s>>2 at sbase(s).
__global__ __launch_bounds__(256) void attn_fin_kernel(
    const float* __restrict__ big, int use_part,
    float* __restrict__ out, float beta_scale)
{
  const int h = blockIdx.y, s = blockIdx.x;
  const int t = threadIdx.x;
  const int w = t >> 6, lane = t & 63;
  const int col = lane & 15, quad = lane >> 4;
  const int q0 = s * 16;

  __shared__ float red[4][64][20];

  f32x4 pv[5];
  #pragma unroll
  for (int nt = 0; nt < 5; ++nt) pv[nt] = (f32x4){0.f, 0.f, 0.f, 0.f};

  if (use_part){
    const int tbase = sbase(s);
    const int nv = (s >> 2) + 1;            // active chunks
    for (int sl = w; sl < nv; sl += 4){
      const uint2* slot = (const uint2*)big + (size_t)(h * TRI16 + tbase + sl) * 320;
      #pragma unroll
      for (int nt = 0; nt < 5; ++nt){
        uint2 v = slot[nt * 64 + lane];
        pv[nt][0] += bf2f((unsigned short)(v.x & 0xffffu));
        pv[nt][1] += bf2f((unsigned short)(v.x >> 16));
        pv[nt][2] += bf2f((unsigned short)(v.y & 0xffffu));
        pv[nt][3] += bf2f((unsigned short)(v.y >> 16));
      }
    }
  } else if (w == 0){
    #pragma unroll
    for (int nt = 0; nt < 5; ++nt)
      #pragma unroll
      for (int r = 0; r < 4; ++r)
        pv[nt][r] = big[((size_t)h * SEQ + q0 + quad * 4 + r) * 80 + 16 * nt + col];
  }

  #pragma unroll
  for (int nt = 0; nt < 5; ++nt)
    *(float4*)&red[w][lane][nt * 4] = (float4){pv[nt][0], pv[nt][1], pv[nt][2], pv[nt][3]};
  __syncthreads();

  if (t < 64){
    #pragma unroll
    for (int nt = 0; nt < 5; ++nt){
      float4 a = *(const float4*)&red[0][t][nt * 4];
      float4 b = *(const float4*)&red[1][t][nt * 4];
      float4 c = *(const float4*)&red[2][t][nt * 4];
      float4 d = *(const float4*)&red[3][t][nt * 4];
      pv[nt][0] = a.x + b.x + c.x + d.x;
      pv[nt][1] = a.y + b.y + c.y + d.y;
      pv[nt][2] = a.z + b.z + c.z + d.z;
      pv[nt][3] = a.w + b.w + c.w + d.w;
    }
    #pragma unroll
    for (int r = 0; r < 4; ++r){
      float den = __shfl(pv[4][r], quad * 16, 64);
      den = fmaxf(den, EPSF);
      float inv_den = 1.f / den;
      float g[4];
      float gsq = 0.f;
      #pragma unroll
      for (int nt = 0; nt < 4; ++nt){ g[nt] = pv[nt][r] * inv_den; gsq += g[nt] * g[nt]; }
      #pragma unroll
      for (int m = 8; m >= 1; m >>= 1) gsq += __shfl_xor(gsq, m, 64);
      float gn = fmaxf(sqrtf(gsq), EPSF);
      float x = fminf(gn, 1.f - 1e-7f);
      float tt2 = x / (1.f + sqrtf(1.f - x * x));
      float scl = (tt2 / gn) * beta_scale;
      const int q = q0 + quad * 4 + r;
      #pragma unroll
      for (int nt = 0; nt < 4; ++nt)
        out[(size_t)q * EDIM + h * HD + 16 * nt + col] = g[nt] * scl;
    }
  }
}

extern "C" void kernel_launch(void* const* d_in, const int* in_sizes, int n_in,
                              void* d_out, int out_size, void* d_ws, size_t ws_size,
                              hipStream_t stream){
  const void* Xq  = d_in[0];
  const void* Xk  = d_in[1];
  const void* Xv  = d_in[2];
  const void* Wq  = d_in[3];
  const void* Wk  = d_in[4];
  const void* Wv  = d_in[5];
  const void* Bq  = d_in[6];
  const void* Bk  = d_in[7];
  const void* Bv  = d_in[8];
  const void* tau = d_in[9];
  const void* gam = d_in[10];

  float* wsf   = (float*)d_ws;
  float* zn    = wsf + ZN_OFF;
  float* stats = wsf + STATS_OFF;
  float* cqs   = wsf + CQ_OFF;
  float* iks   = wsf + IK_OFF;
  unsigned short* u16b = (unsigned short*)(wsf + U16_OFF);
  unsigned short* WT   = u16b + WT_U16;
  unsigned short* qkvb = u16b + QKVB_U16;
  unsigned short* VT   = u16b + VT_U16;
  float* big   = wsf + BIG_OFF;

  const int use_part =
      (ws_size >= (size_t)BIG_OFF * sizeof(float) + (size_t)PART_U16S * 2) ? 1 : 0;

  unsigned short* Qb = qkvb;
  unsigned short* Kb = qkvb + (size_t)H * SEQ * HD;
  float* q2s = stats;
  float* k2s = stats + (size_t)H * SEQ;
  const unsigned short* qprobe = (const unsigned short*)Xq;

  double lb1 = lgamma(EDIM / 2.0) + lgamma(0.5) - lgamma(EDIM / 2.0 + 0.5);
  double lb2 = lgamma(HD / 2.0)   + lgamma(0.5) - lgamma(HD / 2.0 + 0.5);
  float beta_scale = (float)exp(lb1 - lb2);

  wcvt_kernel<<<dim3(64, 3), dim3(256), 0, stream>>>(Wq, Wk, Wv, qprobe, WT, zn);
  hlin_kernel<<<dim3(128, 3), dim3(512), 0, stream>>>(
      Xq, Xk, Xv, WT, Bq, Bk, Bv, zn, qprobe, qkvb, stats, cqs, iks, VT);
  if (!use_part)
    hipMemsetAsync(big, 0, (size_t)ACC_FLOATS * sizeof(float), stream);
  attn_kernel<<<dim3(512, H), dim3(64), 0, stream>>>(
      Qb, Kb, VT, q2s, k2s, cqs, iks, tau, gam, qprobe, big, use_part);
  attn_fin_kernel<<<dim3(128, H), dim3(256), 0, stream>>>(
      big, use_part, (float*)d_out, beta_scale);
}

// Round 7
// 185.974 us; speedup vs baseline: 1.3046x; 1.3046x over previous
//
#include <hip/hip_runtime.h>
#include <cmath>

#define H 8
#define SEQ 2048
#define EDIM 512
#define HD 64
#define EPSF 1e-15f
#define SMS 516   // padded LDS row stride (floats): breaks 4-way bank conflicts

typedef short bf16x8 __attribute__((ext_vector_type(8)));
typedef float f32x4 __attribute__((ext_vector_type(4)));

// workspace layout (float offsets; 16B-aligned)
#define ZN_OFF    16                                // 8 bi-slots x 3 x EDIM partial sums
#define STATS_OFF (ZN_OFF + 24 * EDIM)              // 3*H*SEQ fp32 (rounded q2/k2/v2)
#define CQ_OFF    (STATS_OFF + 3 * H * SEQ)         // H*SEQ: 2/(1-q2)
#define IK_OFF    (CQ_OFF + H * SEQ)                // H*SEQ: 1/(1-k2)
#define PX2_OFF   (IK_OFF + H * SEQ)                // (legacy, keeps offsets stable)
#define U16_OFF   (PX2_OFF + 12288 + 16)
#define WT_U16    0
#define QKVB_U16  (WT_U16 + 3 * EDIM * EDIM)
#define VT_U16    (QKVB_U16 + 3 * SEQ * EDIM)
#define U16_TOTAL (VT_U16 + H * 80 * SEQ)
#define BIG_OFF   (U16_OFF + U16_TOTAL / 2 + 16)    // attn partials (43.3MB)
// Chunk-major decomposition. Slot per (q-subtile s, 64-key chunk c), c<=s>>2.
// Slots per head = sum_s (s/4+1) = 2112; base(s) = s + 2a(a-1) + a*b, a=s>>2, b=s&3.
#define TRI16 2112
#define PART_U16S (H * TRI16 * 1280)                // 21,626,880 u16 = 43.3 MB
#define ACC_FLOATS  (H * SEQ * 80)

__device__ __forceinline__ float bf2f(unsigned short u){
  union { unsigned int i; float f; } v; v.i = ((unsigned int)u) << 16; return v.f;
}
__device__ __forceinline__ unsigned short f2bf(float f){
  union { float f; unsigned int i; } v; v.f = f;
  unsigned int x = v.i;
  unsigned int r = (x + 0x7fffu + ((x >> 16) & 1u)) >> 16;
  return (unsigned short)r;
}

// micro-ops: single-instruction packed bf16 convert + raw transcendentals.
__device__ __forceinline__ unsigned int cvt_pk_bf16(float a, float b){
  unsigned int r;
  asm("v_cvt_pk_bf16_f32 %0, %1, %2" : "=v"(r) : "v"(a), "v"(b));
  return r;
}
__device__ __forceinline__ float vlog2f(float x){
  float r; asm("v_log_f32 %0, %1" : "=v"(r) : "v"(x)); return r;
}
__device__ __forceinline__ float vexp2f(float x){
  float r; asm("v_exp_f32 %0, %1" : "=v"(r) : "v"(x)); return r;
}
__device__ __forceinline__ float vsqrtf(float x){
  float r; asm("v_sqrt_f32 %0, %1" : "=v"(r) : "v"(x)); return r;
}

// inline dtype detect (fp32 data bf16-decodes to huge magnitudes w.p. ~1)
__device__ __forceinline__ int detect_f32(const unsigned short* __restrict__ q){
  const int l = threadIdx.x & 63;
  float mx = 0.f;
  #pragma unroll
  for (int j = 0; j < 4; ++j) mx = fmaxf(mx, fabsf(bf2f(q[l * 4 + j])));
  #pragma unroll
  for (int m = 32; m >= 1; m >>= 1) mx = fmaxf(mx, __shfl_xor(mx, m, 64));
  return mx > 1000.f;
}

// slot base for q-subtile s: sum_{u<s} (u/4 + 1)
__device__ __forceinline__ int sbase(int s){
  const int a = s >> 2, b = s & 3;
  return s + 2 * a * (a - 1) + a * b;
}

// P1: W -> WT bf16 [p][o][i] (transpose) + per-bi partial column sumsq (no atomics).
__global__ __launch_bounds__(256) void wcvt_kernel(
    const void* __restrict__ Wq, const void* __restrict__ Wk, const void* __restrict__ Wv,
    const unsigned short* __restrict__ qprobe,
    unsigned short* __restrict__ WT, float* __restrict__ zn)
{
  const int p = blockIdx.y;
  const int bi = blockIdx.x >> 3, bo = blockIdx.x & 7;
  const void* W = (p == 0) ? Wq : ((p == 1) ? Wk : Wv);
  const int t = threadIdx.x;
  const int isf32 = detect_f32(qprobe);
  __shared__ float tile[64][65];

  #pragma unroll
  for (int j = 0; j < 16; ++j){
    int idx = t + 256 * j;
    int il = idx >> 6, ol = idx & 63;
    float val;
    if (isf32) val = ((const float*)W)[(size_t)(bi * 64 + il) * EDIM + bo * 64 + ol];
    else       val = bf2f(((const unsigned short*)W)[(size_t)(bi * 64 + il) * EDIM + bo * 64 + ol]);
    tile[il][ol] = val;
  }
  __syncthreads();
  if (t < 64){
    float s = 0.f;
    #pragma unroll 8
    for (int i = 0; i < 64; ++i){ float v = tile[i][t]; s += v * v; }
    zn[((size_t)(bi * 3 + p)) * EDIM + bo * 64 + t] = s;
  }
  #pragma unroll
  for (int j = 0; j < 16; ++j){
    int idx = t + 256 * j;
    int ol = idx >> 6, il = idx & 63;
    WT[((size_t)p * EDIM + bo * 64 + ol) * EDIM + bi * 64 + il] = f2bf(tile[il][ol]);
  }
}

// K1 (R29): FUSED projection, 512 threads / 8 waves. Wave (cg, ks): 128 cols x
// K-half. Identical plan to R28 but ALL acc indexing is compile-time constant
// (rule #20: runtime-indexed ext_vector arrays go to scratch — R28's VGPR=72 /
// 2x-duration regression). Exchange/combine use wave-uniform ks branches with
// static unrolls; combined tiles live in own[4]. LDS rows padded to SMS=516.
// Grid (128, 3), 512 threads.
__global__ __launch_bounds__(512) void hlin_kernel(
    const void* __restrict__ Xq, const void* __restrict__ Xk, const void* __restrict__ Xv,
    const unsigned short* __restrict__ WT,
    const void* __restrict__ Bq, const void* __restrict__ Bk, const void* __restrict__ Bv,
    const float* __restrict__ znacc, const unsigned short* __restrict__ qprobe,
    unsigned short* __restrict__ qkvb, float* __restrict__ stats,
    float* __restrict__ cqs, float* __restrict__ iks,
    unsigned short* __restrict__ VT)
{
  const int p = blockIdx.y;
  const void* X  = (p == 0) ? Xq : ((p == 1) ? Xk : Xv);
  const void* Bb = (p == 0) ? Bq : ((p == 1) ? Bk : Bv);
  const int rg = blockIdx.x;
  const int r0 = rg * 16;
  const int t  = threadIdx.x;
  const int w8 = t >> 6, lane = t & 63;
  const int cg = w8 >> 1, ks = w8 & 1;
  const int col = lane & 15, quad = lane >> 4;
  const int isf32 = detect_f32(qprobe);

  __shared__ float smem[16 * SMS];
  __shared__ float sw2[16];
  __shared__ float sx2[2][16];

  const int koff = ks * 256;
  const unsigned short* WTb = WT + ((size_t)p * EDIM + cg * 128 + col) * EDIM + koff;
  const float* Xf = (const float*)X + (size_t)(r0 + col) * EDIM + koff;
  const unsigned short* Xh = (const unsigned short*)X + (size_t)(r0 + col) * EDIM + koff;

  f32x4 acc[8];
  #pragma unroll
  for (int nt = 0; nt < 8; ++nt) acc[nt] = (f32x4){0.f, 0.f, 0.f, 0.f};
  float x2part = 0.f;

  bf16x8 caf, naf;
  bf16x8 cbf[8], nbf[8];
  {
    if (isf32){
      float4 xa = *(const float4*)&Xf[quad * 8];
      float4 xb = *(const float4*)&Xf[quad * 8 + 4];
      float xv[8] = {xa.x, xa.y, xa.z, xa.w, xb.x, xb.y, xb.z, xb.w};
      #pragma unroll
      for (int j = 0; j < 8; ++j){ caf[j] = (short)f2bf(xv[j]); x2part += xv[j] * xv[j]; }
    } else {
      caf = *(const bf16x8*)&Xh[quad * 8];
      #pragma unroll
      for (int j = 0; j < 8; ++j){ float xv = bf2f((unsigned short)caf[j]); x2part += xv * xv; }
    }
    #pragma unroll
    for (int nt = 0; nt < 8; ++nt)
      cbf[nt] = *(const bf16x8*)&WTb[(size_t)nt * 16 * EDIM + quad * 8];
  }

  for (int st = 0; st < 8; ++st){
    if (st + 1 < 8){
      const int off = (st + 1) * 32 + quad * 8;
      if (isf32){
        float4 xa = *(const float4*)&Xf[off];
        float4 xb = *(const float4*)&Xf[off + 4];
        float xv[8] = {xa.x, xa.y, xa.z, xa.w, xb.x, xb.y, xb.z, xb.w};
        #pragma unroll
        for (int j = 0; j < 8; ++j){ naf[j] = (short)f2bf(xv[j]); x2part += xv[j] * xv[j]; }
      } else {
        naf = *(const bf16x8*)&Xh[off];
        #pragma unroll
        for (int j = 0; j < 8; ++j){ float xv = bf2f((unsigned short)naf[j]); x2part += xv * xv; }
      }
      #pragma unroll
      for (int nt = 0; nt < 8; ++nt)
        nbf[nt] = *(const bf16x8*)&WTb[(size_t)nt * 16 * EDIM + off];
    }
    #pragma unroll
    for (int nt = 0; nt < 8; ++nt)
      acc[nt] = __builtin_amdgcn_mfma_f32_16x16x32_bf16(caf, cbf[nt], acc[nt], 0, 0, 0);
    if (st + 1 < 8){
      caf = naf;
      #pragma unroll
      for (int nt = 0; nt < 8; ++nt) cbf[nt] = nbf[nt];
    }
  }
  // per-K-half row x2
  x2part += __shfl_xor(x2part, 16, 64);
  x2part += __shfl_xor(x2part, 32, 64);
  if (cg == 0 && quad == 0) sx2[ks][col] = x2part;

  // partial exchange — STATIC acc indices in wave-uniform branches.
  // ks=0 parks nt 4..7; ks=1 parks nt 0..3.
  if (ks == 0){
    #pragma unroll
    for (int nt = 4; nt < 8; ++nt){
      const int n = cg * 128 + nt * 16 + col;
      #pragma unroll
      for (int r = 0; r < 4; ++r)
        smem[(quad * 4 + r) * SMS + n] = acc[nt][r];
    }
  } else {
    #pragma unroll
    for (int nt = 0; nt < 4; ++nt){
      const int n = cg * 128 + nt * 16 + col;
      #pragma unroll
      for (int r = 0; r < 4; ++r)
        smem[(quad * 4 + r) * SMS + n] = acc[nt][r];
    }
  }
  __syncthreads();
  // combine: own[j] = my tile + partner's parked tile (static indices).
  f32x4 own[4];
  if (ks == 0){
    #pragma unroll
    for (int j = 0; j < 4; ++j){
      const int n = cg * 128 + j * 16 + col;
      own[j] = acc[j];
      #pragma unroll
      for (int r = 0; r < 4; ++r)
        own[j][r] += smem[(quad * 4 + r) * SMS + n];
    }
  } else {
    #pragma unroll
    for (int j = 0; j < 4; ++j){
      const int n = cg * 128 + (4 + j) * 16 + col;
      own[j] = acc[4 + j];
      #pragma unroll
      for (int r = 0; r < 4; ++r)
        own[j][r] += smem[(quad * 4 + r) * SMS + n];
    }
  }
  __syncthreads();   // smem about to be overwritten by transform results

  float lamr[4], lm1[4];
  #pragma unroll
  for (int r = 0; r < 4; ++r){
    float x2r = sx2[0][quad * 4 + r] + sx2[1][quad * 4 + r];
    lamr[r] = 2.f / (1.f - x2r);
    lm1[r] = lamr[r] - 1.f;
  }
  // transform owned tiles (4 per thread, static own[] indices)
  const int ntb = ks * 4;   // used ONLY in address arithmetic
  #pragma unroll
  for (int j = 0; j < 4; ++j){
    const int n = cg * 128 + (ntb + j) * 16 + col;
    float zsum = 0.f;
    #pragma unroll
    for (int bi = 0; bi < 8; ++bi)
      zsum += znacc[((size_t)(bi * 3 + p)) * EDIM + n];
    float znv = fmaxf(sqrtf(zsum), EPSF);
    float rb;
    if (isf32) rb = ((const float*)Bb)[n];
    else       rb = bf2f(((const unsigned short*)Bb)[n]);
    float e2r = __expf(2.f * rb);
    float ie2r = 1.f / e2r;
    float ch = 0.5f * (e2r + ie2r), sh = 0.5f * (e2r - ie2r);
    float izn = 1.f / znv;
    float tz = 2.f * znv;
    #pragma unroll
    for (int r = 0; r < 4; ++r){
      float a = (own[j][r] * lamr[r] * izn) * ch - lm1[r] * sh;
      float b = a + sqrtf(a * a + 1.f);
      float tt = __expf(tz * __logf(b));
      smem[(quad * 4 + r) * SMS + n] = 0.5f * (tt - 1.f / tt);
    }
  }
  __syncthreads();

  // row sumsq: 32 threads per row
  {
    int row = t >> 5, l = t & 31;
    float s = 0.f;
    for (int o = l; o < EDIM; o += 32){ float wv = smem[row * SMS + o]; s += wv * wv; }
    #pragma unroll
    for (int m = 16; m >= 1; m >>= 1) s += __shfl_xor(s, m, 32);
    if (l == 0) sw2[row] = s;
  }
  __syncthreads();

  // output: thread halves handle 8 rows each
  const int th = t & 255;
  const int half = t >> 8;
  const int o0 = 2 * th;
  const int h0 = th >> 5;
  const int d0 = o0 & 63;
  const int l5 = th & 31;
  #pragma unroll
  for (int jr = 0; jr < 8; ++jr){
    const int rr = half * 8 + jr;
    float inv = 1.f / (1.f + sqrtf(1.f + sw2[rr]));
    unsigned short b0 = f2bf(smem[rr * SMS + o0] * inv);
    unsigned short b1 = f2bf(smem[rr * SMS + o0 + 1] * inv);
    float r0v = bf2f(b0), r1v = bf2f(b1);
    int s = r0 + rr;
    unsigned int* dst = (unsigned int*)&qkvb[(((size_t)p * H + h0) * SEQ + s) * HD + d0];
    *dst = (unsigned int)b0 | ((unsigned int)b1 << 16);
    float ss = r0v * r0v + r1v * r1v;
    #pragma unroll
    for (int m = 16; m >= 1; m >>= 1) ss += __shfl_xor(ss, m, 64);
    if (p == 2){
      float lam = 2.f / (1.f - ss);
      VT[((size_t)h0 * 80 + d0) * SEQ + s]     = f2bf(r0v * lam);
      VT[((size_t)h0 * 80 + d0 + 1) * SEQ + s] = f2bf(r1v * lam);
      if (l5 < 16)
        VT[((size_t)h0 * 80 + 64 + l5) * SEQ + s] = (l5 == 0) ? f2bf(lam - 1.f) : 0;
    }
    if (l5 == 0){
      stats[((size_t)p * H + h0) * SEQ + s] = ss;
      if (p == 0) cqs[(size_t)h0 * SEQ + s] = 2.f / (1.f - ss);
      if (p == 1) iks[(size_t)h0 * SEQ + s] = 1.f / (1.f - ss);
    }
  }
}

// ---- attention helpers ----
__device__ __forceinline__ uint4 xpose32(unsigned int tlo0, unsigned int tlo1,
                                         unsigned int thi0, unsigned int thi1,
                                         int srcA, int srcB, int tsel){
  unsigned int a0 = (unsigned int)__shfl((int)tlo0, srcA, 64);
  unsigned int a1 = (unsigned int)__shfl((int)tlo1, srcA, 64);
  unsigned int b0 = (unsigned int)__shfl((int)thi0, srcA, 64);
  unsigned int b1 = (unsigned int)__shfl((int)thi1, srcA, 64);
  unsigned int c0 = (unsigned int)__shfl((int)tlo0, srcB, 64);
  unsigned int c1 = (unsigned int)__shfl((int)tlo1, srcB, 64);
  unsigned int d0 = (unsigned int)__shfl((int)thi0, srcB, 64);
  unsigned int d1 = (unsigned int)__shfl((int)thi1, srcB, 64);
  uint4 r;
  r.x = tsel ? a1 : a0;
  r.y = tsel ? b1 : b0;
  r.z = tsel ? c1 : c0;
  r.w = tsel ? d1 : d0;
  return r;
}

__device__ __forceinline__ void score4(
    const f32x4& s4, const float4& k2v, const float4& ikv,
    float cq, float cqq2, float m2cq, int kbase, int qmax, int quad,
    float m_et, float m_g2, unsigned int& lo, unsigned int& hi)
{
  float w[4];
  #pragma unroll
  for (int r = 0; r < 4; ++r){
    float k2 = (r == 0) ? k2v.x : (r == 1) ? k2v.y : (r == 2) ? k2v.z : k2v.w;
    float ik = (r == 0) ? ikv.x : (r == 1) ? ikv.y : (r == 2) ? ikv.z : ikv.w;
    float t1 = __builtin_fmaf(k2, cq, cqq2);
    t1 = __builtin_fmaf(m2cq, s4[r], t1);
    float u = fmaxf(t1 * ik, 1e-7f);
    float z = 1.f + u + vsqrtf(u * (u + 2.f));
    float wv = vexp2f(__builtin_fmaf(vlog2f(z), m_et, m_g2));
    const int key = kbase + quad * 4 + r;
    w[r] = (key > qmax) ? 0.f : wv;
  }
  lo = cvt_pk_bf16(w[0], w[1]);
  hi = cvt_pk_bf16(w[2], w[3]);
}

// K3a: attention — R25 structure (proven). Chunk-major: each wave owns one
// 64-key chunk c and a slice of 8 q-subtiles; K/VT/k2/ik fragments are
// loop-invariant; inner loop walks q-subtile pairs with 1-deep Q prefetch.
// Grid (512, H), 64 threads.
template<int NITER>
__device__ __forceinline__ void attn_qloop(
    int s0, int c, int kBeg, int col, int quad, int lane,
    const unsigned short* __restrict__ Qh,
    const bf16x8 (&kf0)[4], const bf16x8 (&kf1)[4],
    const float4 (&ck2)[4], const float4 (&cik)[4],
    const bf16x8 (&vf0)[5], const bf16x8 (&vf1)[5],
    const float* __restrict__ q2s, const float* __restrict__ cqs,
    float m_et, float m_g2, int srcA, int srcB, int tsel,
    float* __restrict__ big, int h, int use_part)
{
  bf16x8 qA0 = *(const bf16x8*)&Qh[(size_t)(s0 * 16 + col) * HD + quad * 8];
  bf16x8 qA1 = *(const bf16x8*)&Qh[(size_t)(s0 * 16 + col) * HD + 32 + quad * 8];
  bf16x8 qB0 = *(const bf16x8*)&Qh[(size_t)((s0 + 1) * 16 + col) * HD + quad * 8];
  bf16x8 qB1 = *(const bf16x8*)&Qh[(size_t)((s0 + 1) * 16 + col) * HD + 32 + quad * 8];
  float q2A = q2s[s0 * 16 + col],       cqA = cqs[s0 * 16 + col];
  float q2B = q2s[(s0 + 1) * 16 + col], cqB = cqs[(s0 + 1) * 16 + col];

  #pragma unroll
  for (int i = 0; i < NITER; ++i){
    const int sA = s0 + 2 * i, sB = sA + 1;
    bf16x8 nA0, nA1, nB0, nB1;
    float nq2A, ncqA, nq2B, ncqB;
    if (i + 1 < NITER){
      const int tA = (sA + 2) * 16 + col, tB = (sA + 3) * 16 + col;
      nA0 = *(const bf16x8*)&Qh[(size_t)tA * HD + quad * 8];
      nA1 = *(const bf16x8*)&Qh[(size_t)tA * HD + 32 + quad * 8];
      nB0 = *(const bf16x8*)&Qh[(size_t)tB * HD + quad * 8];
      nB1 = *(const bf16x8*)&Qh[(size_t)tB * HD + 32 + quad * 8];
      nq2A = q2s[tA]; ncqA = cqs[tA];
      nq2B = q2s[tB]; ncqB = cqs[tB];
    }

    const float cqq2A = cqA * q2A, m2cqA = -2.f * cqA;
    const float cqq2B = cqB * q2B, m2cqB = -2.f * cqB;
    const int qmaxA = sA * 16 + col, qmaxB = sB * 16 + col;

    f32x4 sSA[4], sSB[4];
    __builtin_amdgcn_s_setprio(1);
    #pragma unroll
    for (int g = 0; g < 4; ++g){
      f32x4 z4 = (f32x4){0.f, 0.f, 0.f, 0.f};
      sSA[g] = __builtin_amdgcn_mfma_f32_16x16x32_bf16(kf0[g], qA0, z4, 0, 0, 0);
      sSA[g] = __builtin_amdgcn_mfma_f32_16x16x32_bf16(kf1[g], qA1, sSA[g], 0, 0, 0);
      sSB[g] = __builtin_amdgcn_mfma_f32_16x16x32_bf16(kf0[g], qB0, z4, 0, 0, 0);
      sSB[g] = __builtin_amdgcn_mfma_f32_16x16x32_bf16(kf1[g], qB1, sSB[g], 0, 0, 0);
    }
    __builtin_amdgcn_s_setprio(0);

    unsigned int loA[4], hiA[4], loB[4], hiB[4];
    #pragma unroll
    for (int g = 0; g < 4; ++g){
      score4(sSA[g], ck2[g], cik[g], cqA, cqq2A, m2cqA, kBeg + g * 16, qmaxA, quad,
             m_et, m_g2, loA[g], hiA[g]);
      score4(sSB[g], ck2[g], cik[g], cqB, cqq2B, m2cqB, kBeg + g * 16, qmaxB, quad,
             m_et, m_g2, loB[g], hiB[g]);
    }

    union { uint4 u; bf16x8 v; } pA01, pA23, pB01, pB23;
    pA01.u = xpose32(loA[0], loA[1], hiA[0], hiA[1], srcA, srcB, tsel);
    pA23.u = xpose32(loA[2], loA[3], hiA[2], hiA[3], srcA, srcB, tsel);
    pB01.u = xpose32(loB[0], loB[1], hiB[0], hiB[1], srcA, srcB, tsel);
    pB23.u = xpose32(loB[2], loB[3], hiB[2], hiB[3], srcA, srcB, tsel);

    f32x4 pvA[5], pvB[5];
    __builtin_amdgcn_s_setprio(1);
    #pragma unroll
    for (int nt = 0; nt < 5; ++nt){
      f32x4 z4 = (f32x4){0.f, 0.f, 0.f, 0.f};
      pvA[nt] = __builtin_amdgcn_mfma_f32_16x16x32_bf16(pA01.v, vf0[nt], z4, 0, 0, 0);
      pvA[nt] = __builtin_amdgcn_mfma_f32_16x16x32_bf16(pA23.v, vf1[nt], pvA[nt], 0, 0, 0);
      pvB[nt] = __builtin_amdgcn_mfma_f32_16x16x32_bf16(pB01.v, vf0[nt], z4, 0, 0, 0);
      pvB[nt] = __builtin_amdgcn_mfma_f32_16x16x32_bf16(pB23.v, vf1[nt], pvB[nt], 0, 0, 0);
    }
    __builtin_amdgcn_s_setprio(0);

    if (use_part){
      uint2* slotA = (uint2*)big + (size_t)(h * TRI16 + sbase(sA) + c) * 320;
      uint2* slotB = (uint2*)big + (size_t)(h * TRI16 + sbase(sB) + c) * 320;
      #pragma unroll
      for (int nt = 0; nt < 5; ++nt){
        uint2 pk;
        pk.x = cvt_pk_bf16(pvA[nt][0], pvA[nt][1]);
        pk.y = cvt_pk_bf16(pvA[nt][2], pvA[nt][3]);
        slotA[nt * 64 + lane] = pk;
        pk.x = cvt_pk_bf16(pvB[nt][0], pvB[nt][1]);
        pk.y = cvt_pk_bf16(pvB[nt][2], pvB[nt][3]);
        slotB[nt * 64 + lane] = pk;
      }
    } else {
      #pragma unroll
      for (int r = 0; r < 4; ++r){
        float* rowA = big + ((size_t)h * SEQ + sA * 16 + quad * 4 + r) * 80;
        float* rowB = big + ((size_t)h * SEQ + sB * 16 + quad * 4 + r) * 80;
        #pragma unroll
        for (int nt = 0; nt < 5; ++nt){
          atomicAdd(&rowA[16 * nt + col], pvA[nt][r]);
          atomicAdd(&rowB[16 * nt + col], pvB[nt][r]);
        }
      }
    }

    if (i + 1 < NITER){
      qA0 = nA0; qA1 = nA1; qB0 = nB0; qB1 = nB1;
      q2A = nq2A; cqA = ncqA; q2B = nq2B; cqB = ncqB;
    }
  }
}

__global__ __launch_bounds__(64, 2) void attn_kernel(
    const unsigned short* __restrict__ Qb, const unsigned short* __restrict__ Kb,
    const unsigned short* __restrict__ VT,
    const float* __restrict__ q2s_all, const float* __restrict__ k2s_all,
    const float* __restrict__ cqs_all, const float* __restrict__ iks_all,
    const void* __restrict__ tau, const void* __restrict__ gam,
    const unsigned short* __restrict__ qprobe,
    float* __restrict__ big, int use_part)
{
  const int h = blockIdx.y;
  const int c = blockIdx.x >> 4;            // 64-key chunk
  const int j = blockIdx.x & 15;            // q-slice within chunk
  const int nsl = (33 - c) >> 1;            // ceil((32-c)/2)
  if (j >= nsl) return;
  const int kBeg = c * 64;
  const int s0 = 4 * c + 8 * j;             // first q-subtile of slice
  const int rem = 128 - s0;                 // subtiles remaining (>=4, mult of 4)
  const int lane = threadIdx.x;
  const int col = lane & 15, quad = lane >> 4;

  const unsigned short* Qh  = Qb + (size_t)h * SEQ * HD;
  const unsigned short* Kh  = Kb + (size_t)h * SEQ * HD;
  const unsigned short* VTh = VT + (size_t)h * 80 * SEQ;
  const float* q2s = q2s_all + (size_t)h * SEQ;
  const float* k2s = k2s_all + (size_t)h * SEQ;
  const float* cqs = cqs_all + (size_t)h * SEQ;
  const float* iks = iks_all + (size_t)h * SEQ;

  const int isf32 = detect_f32(qprobe);
  float tauv, gamv;
  if (isf32){ tauv = ((const float*)tau)[0]; gamv = ((const float*)gam)[0]; }
  else      { tauv = bf2f(((const unsigned short*)tau)[0]);
              gamv = bf2f(((const unsigned short*)gam)[0]); }
  // w = exp(-e^tau * ln z - gam) = 2^( log2(z)*(-e^tau) + (-gam*log2e) )
  const float m_et = -__expf(tauv);
  const float m_g2 = -gamv * 1.44269504088896340736f;

  const int srcA = ((quad & 1) * 2) * 16 + col;
  const int srcB = srcA + 16;
  const int tsel = quad >> 1;

  // loop-invariant K-side fragments: 8 K + 10 VT + 8 stat loads, once per wave.
  bf16x8 kf0[4], kf1[4];
  float4 ck2[4], cik[4];
  #pragma unroll
  for (int g = 0; g < 4; ++g){
    kf0[g] = *(const bf16x8*)&Kh[(size_t)(kBeg + g * 16 + col) * HD + quad * 8];
    kf1[g] = *(const bf16x8*)&Kh[(size_t)(kBeg + g * 16 + col) * HD + 32 + quad * 8];
    ck2[g] = *(const float4*)&k2s[kBeg + g * 16 + quad * 4];
    cik[g] = *(const float4*)&iks[kBeg + g * 16 + quad * 4];
  }
  bf16x8 vf0[5], vf1[5];
  #pragma unroll
  for (int nt = 0; nt < 5; ++nt){
    vf0[nt] = *(const bf16x8*)&VTh[(size_t)(16 * nt + col) * SEQ + kBeg + quad * 8];
    vf1[nt] = *(const bf16x8*)&VTh[(size_t)(16 * nt + col) * SEQ + kBeg + 32 + quad * 8];
  }

  if (rem >= 8)
    attn_qloop<4>(s0, c, kBeg, col, quad, lane, Qh, kf0, kf1, ck2, cik, vf0, vf1,
                  q2s, cqs, m_et, m_g2, srcA, srcB, tsel, big, h, use_part);
  else
    attn_qloop<2>(s0, c, kBeg, col, quad, lane, Qh, kf0, kf1, ck2, cik, vf0, vf1,
                  q2s, cqs, m_et, m_g2, srcA, srcB, tsel, big, h, use_part);
}

// K3b: bf16-slice-sum + LDS reduce + gyromidpoint. Grid (128, H), 256 thr.
// blockIdx.x = q-subtile s; reduce over chunks c = 0..s>>2 at sbase(s).
__global__ __launch_bounds__(256) void attn_fin_kernel(
    const float* __restrict__ big, int use_part,
    float* __restrict__ out, float beta_scale)
{
  const int h = blockIdx.y, s = blockIdx.x;
  const int t = threadIdx.x;
  const int w = t >> 6, lane = t & 63;
  const int col = lane & 15, quad = lane >> 4;
  const int q0 = s * 16;

  __shared__ float red[4][64][20];

  f32x4 pv[5];
  #pragma unroll
  for (int nt = 0; nt < 5; ++nt) pv[nt] = (f32x4){0.f, 0.f, 0.f, 0.f};

  if (use_part){
    const int tbase = sbase(s);
    const int nv = (s >> 2) + 1;            // active chunks
    for (int sl = w; sl < nv; sl += 4){
      const uint2* slot = (const uint2*)big + (size_t)(h * TRI16 + tbase + sl) * 320;
      #pragma unroll
      for (int nt = 0; nt < 5; ++nt){
        uint2 v = slot[nt * 64 + lane];
        pv[nt][0] += bf2f((unsigned short)(v.x & 0xffffu));
        pv[nt][1] += bf2f((unsigned short)(v.x >> 16));
        pv[nt][2] += bf2f((unsigned short)(v.y & 0xffffu));
        pv[nt][3] += bf2f((unsigned short)(v.y >> 16));
      }
    }
  } else if (w == 0){
    #pragma unroll
    for (int nt = 0; nt < 5; ++nt)
      #pragma unroll
      for (int r = 0; r < 4; ++r)
        pv[nt][r] = big[((size_t)h * SEQ + q0 + quad * 4 + r) * 80 + 16 * nt + col];
  }

  #pragma unroll
  for (int nt = 0; nt < 5; ++nt)
    *(float4*)&red[w][lane][nt * 4] = (float4){pv[nt][0], pv[nt][1], pv[nt][2], pv[nt][3]};
  __syncthreads();

  if (t < 64){
    #pragma unroll
    for (int nt = 0; nt < 5; ++nt){
      float4 a = *(const float4*)&red[0][t][nt * 4];
      float4 b = *(const float4*)&red[1][t][nt * 4];
      float4 c = *(const float4*)&red[2][t][nt * 4];
      float4 d = *(const float4*)&red[3][t][nt * 4];
      pv[nt][0] = a.x + b.x + c.x + d.x;
      pv[nt][1] = a.y + b.y + c.y + d.y;
      pv[nt][2] = a.z + b.z + c.z + d.z;
      pv[nt][3] = a.w + b.w + c.w + d.w;
    }
    #pragma unroll
    for (int r = 0; r < 4; ++r){
      float den = __shfl(pv[4][r], quad * 16, 64);
      den = fmaxf(den, EPSF);
      float inv_den = 1.f / den;
      float g[4];
      float gsq = 0.f;
      #pragma unroll
      for (int nt = 0; nt < 4; ++nt){ g[nt] = pv[nt][r] * inv_den; gsq += g[nt] * g[nt]; }
      #pragma unroll
      for (int m = 8; m >= 1; m >>= 1) gsq += __shfl_xor(gsq, m, 64);
      float gn = fmaxf(sqrtf(gsq), EPSF);
      float x = fminf(gn, 1.f - 1e-7f);
      float tt2 = x / (1.f + sqrtf(1.f - x * x));
      float scl = (tt2 / gn) * beta_scale;
      const int q = q0 + quad * 4 + r;
      #pragma unroll
      for (int nt = 0; nt < 4; ++nt)
        out[(size_t)q * EDIM + h * HD + 16 * nt + col] = g[nt] * scl;
    }
  }
}

extern "C" void kernel_launch(void* const* d_in, const int* in_sizes, int n_in,
                              void* d_out, int out_size, void* d_ws, size_t ws_size,
                              hipStream_t stream){
  const void* Xq  = d_in[0];
  const void* Xk  = d_in[1];
  const void* Xv  = d_in[2];
  const void* Wq  = d_in[3];
  const void* Wk  = d_in[4];
  const void* Wv  = d_in[5];
  const void* Bq  = d_in[6];
  const void* Bk  = d_in[7];
  const void* Bv  = d_in[8];
  const void* tau = d_in[9];
  const void* gam = d_in[10];

  float* wsf   = (float*)d_ws;
  float* zn    = wsf + ZN_OFF;
  float* stats = wsf + STATS_OFF;
  float* cqs   = wsf + CQ_OFF;
  float* iks   = wsf + IK_OFF;
  unsigned short* u16b = (unsigned short*)(wsf + U16_OFF);
  unsigned short* WT   = u16b + WT_U16;
  unsigned short* qkvb = u16b + QKVB_U16;
  unsigned short* VT   = u16b + VT_U16;
  float* big   = wsf + BIG_OFF;

  const int use_part =
      (ws_size >= (size_t)BIG_OFF * sizeof(float) + (size_t)PART_U16S * 2) ? 1 : 0;

  unsigned short* Qb = qkvb;
  unsigned short* Kb = qkvb + (size_t)H * SEQ * HD;
  float* q2s = stats;
  float* k2s = stats + (size_t)H * SEQ;
  const unsigned short* qprobe = (const unsigned short*)Xq;

  double lb1 = lgamma(EDIM / 2.0) + lgamma(0.5) - lgamma(EDIM / 2.0 + 0.5);
  double lb2 = lgamma(HD / 2.0)   + lgamma(0.5) - lgamma(HD / 2.0 + 0.5);
  float beta_scale = (float)exp(lb1 - lb2);

  wcvt_kernel<<<dim3(64, 3), dim3(256), 0, stream>>>(Wq, Wk, Wv, qprobe, WT, zn);
  hlin_kernel<<<dim3(128, 3), dim3(512), 0, stream>>>(
      Xq, Xk, Xv, WT, Bq, Bk, Bv, zn, qprobe, qkvb, stats, cqs, iks, VT);
  if (!use_part)
    hipMemsetAsync(big, 0, (size_t)ACC_FLOATS * sizeof(float), stream);
  attn_kernel<<<dim3(512, H), dim3(64), 0, stream>>>(
      Qb, Kb, VT, q2s, k2s, cqs, iks, tau, gam, qprobe, big, use_part);
  attn_fin_kernel<<<dim3(128, H), dim3(256), 0, stream>>>(
      big, use_part, (float*)d_out, beta_scale);
}